// Round 1
// baseline (220.522 us; speedup 1.0000x reference)
//
#include <hip/hip_runtime.h>

#define NN 16384
#define KK 64
#define DD 128
#define PP 8
#define NB 32

__device__ __forceinline__ float silu_f(float v) {
    return v / (1.0f + __expf(-v));
}

// out[r][c] = sum_k A[r][k] * W[c*DD + k]  (i.e. A @ W^T), 32-row tile,
// 256 threads: c0=(t&31)*4 (4 cols), r0=(t>>5)*4 (4 rows), acc[4][4].
__device__ __forceinline__ void gemm_tile32(const float (*__restrict__ A)[DD],
                                            const float* __restrict__ W,
                                            int r0, int c0, float (*acc)[4]) {
#pragma unroll
    for (int j = 0; j < 4; ++j)
#pragma unroll
        for (int m = 0; m < 4; ++m) acc[j][m] = 0.0f;

#pragma unroll 2
    for (int k0 = 0; k0 < DD; k0 += 4) {
        float w[4][4];
#pragma unroll
        for (int m = 0; m < 4; ++m)
            *(float4*)&w[m][0] = *(const float4*)&W[(size_t)(c0 + m) * DD + k0];
#pragma unroll
        for (int j = 0; j < 4; ++j) {
            float xv[4];
            *(float4*)&xv[0] = *(const float4*)&A[r0 + j][k0];
#pragma unroll
            for (int m = 0; m < 4; ++m) {
#pragma unroll
                for (int kk = 0; kk < 4; ++kk)
                    acc[j][m] = fmaf(xv[kk], w[m][kk], acc[j][m]);
            }
        }
    }
}

// ---------------- kernel 1: pre-MLP + residual + LayerNorm -> xres ----------
__global__ __launch_bounds__(256, 2) void k_premlp(
        const float* __restrict__ x, const float* __restrict__ W1,
        const float* __restrict__ W2, const float* __restrict__ gamma,
        const float* __restrict__ beta, float* __restrict__ xres) {
    __shared__ float xs[32][DD];
    __shared__ float t1[32][DD];
    const int t = threadIdx.x;
    const int n0 = blockIdx.x * 32;

#pragma unroll
    for (int i = 0; i < 4; ++i)
        ((float4*)&xs[0][0])[t + i * 256] =
            ((const float4*)(x + (size_t)n0 * DD))[t + i * 256];
    __syncthreads();

    const int c0 = (t & 31) * 4;
    const int r0 = (t >> 5) * 4;
    float acc[4][4];

    gemm_tile32(xs, W1, r0, c0, acc);
#pragma unroll
    for (int j = 0; j < 4; ++j) {
        float4 o;
        o.x = silu_f(acc[j][0]); o.y = silu_f(acc[j][1]);
        o.z = silu_f(acc[j][2]); o.w = silu_f(acc[j][3]);
        *(float4*)&t1[r0 + j][c0] = o;
    }
    __syncthreads();

    gemm_tile32(t1, W2, r0, c0, acc);
#pragma unroll
    for (int j = 0; j < 4; ++j) {
        float4 xv = *(const float4*)&xs[r0 + j][c0];
        float4 o;
        o.x = xv.x + silu_f(acc[j][0]);
        o.y = xv.y + silu_f(acc[j][1]);
        o.z = xv.z + silu_f(acc[j][2]);
        o.w = xv.w + silu_f(acc[j][3]);
        *(float4*)&xs[r0 + j][c0] = o;   // owner-only read+write, no barrier needed
    }
    __syncthreads();

    // LayerNorm each of the 32 rows (one wave handles rows wid, wid+4, ...)
    const int wid = t >> 6, lane = t & 63;
    const float g0 = gamma[lane], g1 = gamma[lane + 64];
    const float be0 = beta[lane], be1 = beta[lane + 64];
    for (int r = wid; r < 32; r += 4) {
        float a = xs[r][lane], b = xs[r][lane + 64];
        float s = a + b, sq = a * a + b * b;
#pragma unroll
        for (int off = 32; off > 0; off >>= 1) {
            s  += __shfl_xor(s, off);
            sq += __shfl_xor(sq, off);
        }
        float mu  = s * (1.0f / 128.0f);
        float var = sq * (1.0f / 128.0f) - mu * mu;
        float rs  = rsqrtf(var + 1e-5f);
        float* orow = xres + (size_t)(n0 + r) * DD;
        orow[lane]      = (a - mu) * rs * g0 + be0;
        orow[lane + 64] = (b - mu) * rs * g1 + be1;
    }
}

// ---------------- kernel 2: segmented scatter  sf[b,k,d] += trig*xres -------
__global__ __launch_bounds__(256) void k_scatter(
        const float* __restrict__ xres, const float* __restrict__ kdr,
        const float* __restrict__ damp, const int* __restrict__ batch,
        float* __restrict__ sf_r, float* __restrict__ sf_i) {
    __shared__ float xl[64][DD];   // 32KB
    __shared__ float rl[64][KK];   // 16KB
    __shared__ float il[64][KK];   // 16KB
    const int t = threadIdx.x;
    const int n0 = blockIdx.x * 64;

#pragma unroll
    for (int i = 0; i < 8; ++i)
        ((float4*)&xl[0][0])[t + i * 256] =
            ((const float4*)(xres + (size_t)n0 * DD))[t + i * 256];
#pragma unroll
    for (int i = 0; i < 16; ++i) {
        int idx = t + i * 256;          // 0..4095
        int r = idx >> 6, k = idx & 63;
        float kv = kdr[(size_t)(n0 + r) * KK + k];
        float dv = damp[(size_t)(n0 + r) * KK + k];
        float s, c;
        __sincosf(kv, &s, &c);
        rl[r][k] = c * dv;
        il[r][k] = s * dv;
    }
    __syncthreads();

    const int d  = t & 127;
    const int kg = (t >> 7) * 32;       // thread owns k in [kg, kg+32)
    float accr[32], acci[32];
#pragma unroll
    for (int j = 0; j < 32; ++j) { accr[j] = 0.0f; acci[j] = 0.0f; }

    int curb = batch[n0];
    for (int r = 0; r < 64; ++r) {
        int b = batch[n0 + r];
        if (b != curb) {                 // uniform branch (b is row-level)
#pragma unroll
            for (int j = 0; j < 32; ++j) {
                atomicAdd(&sf_r[(size_t)(curb * KK + kg + j) * DD + d], accr[j]);
                atomicAdd(&sf_i[(size_t)(curb * KK + kg + j) * DD + d], acci[j]);
                accr[j] = 0.0f; acci[j] = 0.0f;
            }
            curb = b;
        }
        float xv = xl[r][d];
#pragma unroll
        for (int q = 0; q < 8; ++q) {
            float4 rv = *(const float4*)&rl[r][kg + q * 4];
            float4 iv = *(const float4*)&il[r][kg + q * 4];
            accr[q * 4 + 0] = fmaf(rv.x, xv, accr[q * 4 + 0]);
            accr[q * 4 + 1] = fmaf(rv.y, xv, accr[q * 4 + 1]);
            accr[q * 4 + 2] = fmaf(rv.z, xv, accr[q * 4 + 2]);
            accr[q * 4 + 3] = fmaf(rv.w, xv, accr[q * 4 + 3]);
            acci[q * 4 + 0] = fmaf(iv.x, xv, acci[q * 4 + 0]);
            acci[q * 4 + 1] = fmaf(iv.y, xv, acci[q * 4 + 1]);
            acci[q * 4 + 2] = fmaf(iv.z, xv, acci[q * 4 + 2]);
            acci[q * 4 + 3] = fmaf(iv.w, xv, acci[q * 4 + 3]);
        }
    }
#pragma unroll
    for (int j = 0; j < 32; ++j) {
        atomicAdd(&sf_r[(size_t)(curb * KK + kg + j) * DD + d], accr[j]);
        atomicAdd(&sf_i[(size_t)(curb * KK + kg + j) * DD + d], acci[j]);
    }
}

// ---------------- kernel 3: sf' = kfilter(k,d) * sf -------------------------
__global__ __launch_bounds__(256) void k_filter(
        const float* __restrict__ dp, const float* __restrict__ wup,
        float* __restrict__ sf_r, float* __restrict__ sf_i) {
    int idx = blockIdx.x * 256 + threadIdx.x;    // < NB*KK*DD
    int dcol = idx & 127;
    int k = (idx >> 7) & 63;
    float kf = 0.0f;
#pragma unroll
    for (int p = 0; p < PP; ++p)
        kf = fmaf(dp[k * PP + p], wup[dcol * PP + p], kf);
    sf_r[idx] *= kf;
    sf_i[idx] *= kf;
}

// ---------------- kernel 4: gather + message + post-MLP -> out --------------
__global__ __launch_bounds__(256, 2) void k_gather(
        const float* __restrict__ x, const float* __restrict__ kdr,
        const float* __restrict__ damp, const int* __restrict__ batch,
        const float* __restrict__ sfr, const float* __restrict__ sfi,
        const float* __restrict__ W1, const float* __restrict__ W2,
        float* __restrict__ out) {
    __shared__ float bufA[32][DD];   // trig: real at [r][k], imag at [r][64+k]; later t1
    __shared__ float xs[32][DD];
    const int t = threadIdx.x;
    const int n0 = blockIdx.x * 32;

#pragma unroll
    for (int i = 0; i < 8; ++i) {
        int idx = t + i * 256;          // 0..2047
        int r = idx >> 6, k = idx & 63;
        float kv = kdr[(size_t)(n0 + r) * KK + k];
        float dv = damp[(size_t)(n0 + r) * KK + k];
        float s, c;
        __sincosf(kv, &s, &c);
        bufA[r][k]      = c * dv;
        bufA[r][64 + k] = s * dv;
    }
    __syncthreads();

    const int c0 = (t & 31) * 4;
    const int r0 = (t >> 5) * 4;
    float acc[4][4];
#pragma unroll
    for (int j = 0; j < 4; ++j)
#pragma unroll
        for (int m = 0; m < 4; ++m) acc[j][m] = 0.0f;

    const int b_lo = batch[n0 + r0];
    const int b_hi = batch[n0 + r0 + 3];
    if (b_lo == b_hi) {
        // fast path: all 4 rows in same segment -> sf column regs reused 4x
        const float* pr = sfr + (size_t)b_lo * KK * DD + c0;
        const float* pi = sfi + (size_t)b_lo * KK * DD + c0;
        for (int k0 = 0; k0 < KK; k0 += 4) {
            float sr[4][4], si[4][4];
#pragma unroll
            for (int kk = 0; kk < 4; ++kk) {
                *(float4*)&sr[kk][0] = *(const float4*)(pr + (size_t)(k0 + kk) * DD);
                *(float4*)&si[kk][0] = *(const float4*)(pi + (size_t)(k0 + kk) * DD);
            }
#pragma unroll
            for (int j = 0; j < 4; ++j) {
                float rv[4], iv[4];
                *(float4*)&rv[0] = *(const float4*)&bufA[r0 + j][k0];
                *(float4*)&iv[0] = *(const float4*)&bufA[r0 + j][64 + k0];
#pragma unroll
                for (int kk = 0; kk < 4; ++kk) {
#pragma unroll
                    for (int m = 0; m < 4; ++m)
                        acc[j][m] += rv[kk] * sr[kk][m] + iv[kk] * si[kk][m];
                }
            }
        }
    } else {
        // slow path: segment boundary inside this thread's rows (rare)
#pragma unroll 1
        for (int j = 0; j < 4; ++j) {
            int b = batch[n0 + r0 + j];
            const float* pr = sfr + (size_t)b * KK * DD + c0;
            const float* pi = sfi + (size_t)b * KK * DD + c0;
#pragma unroll 1
            for (int k = 0; k < KK; ++k) {
                float rv = bufA[r0 + j][k];
                float iv = bufA[r0 + j][64 + k];
                float4 sr = *(const float4*)(pr + (size_t)k * DD);
                float4 si = *(const float4*)(pi + (size_t)k * DD);
                acc[j][0] += rv * sr.x + iv * si.x;
                acc[j][1] += rv * sr.y + iv * si.y;
                acc[j][2] += rv * sr.z + iv * si.z;
                acc[j][3] += rv * sr.w + iv * si.w;
            }
        }
    }

    // xs = x_scalar + ewald_message
#pragma unroll
    for (int j = 0; j < 4; ++j) {
        float4 xv = *(const float4*)(x + (size_t)(n0 + r0 + j) * DD + c0);
        float4 o;
        o.x = xv.x + acc[j][0];
        o.y = xv.y + acc[j][1];
        o.z = xv.z + acc[j][2];
        o.w = xv.w + acc[j][3];
        *(float4*)&xs[r0 + j][c0] = o;
    }
    __syncthreads();

    gemm_tile32(xs, W1, r0, c0, acc);
#pragma unroll
    for (int j = 0; j < 4; ++j) {
        float4 o;
        o.x = silu_f(acc[j][0]); o.y = silu_f(acc[j][1]);
        o.z = silu_f(acc[j][2]); o.w = silu_f(acc[j][3]);
        *(float4*)&bufA[r0 + j][c0] = o;
    }
    __syncthreads();

    gemm_tile32(bufA, W2, r0, c0, acc);
#pragma unroll
    for (int j = 0; j < 4; ++j) {
        float4 xv = *(const float4*)&xs[r0 + j][c0];
        float4 o;
        o.x = xv.x + silu_f(acc[j][0]);
        o.y = xv.y + silu_f(acc[j][1]);
        o.z = xv.z + silu_f(acc[j][2]);
        o.w = xv.w + silu_f(acc[j][3]);
        *(float4*)(out + (size_t)(n0 + r0 + j) * DD + c0) = o;
    }
}

extern "C" void kernel_launch(void* const* d_in, const int* in_sizes, int n_in,
                              void* d_out, int out_size, void* d_ws, size_t ws_size,
                              hipStream_t stream) {
    const float* x      = (const float*)d_in[0];
    const float* kdr    = (const float*)d_in[1];
    const float* damp   = (const float*)d_in[2];
    const int*   batch  = (const int*)d_in[3];
    const float* dp     = (const float*)d_in[4];
    const float* W_pre1 = (const float*)d_in[5];
    const float* W_pre2 = (const float*)d_in[6];
    const float* gamma  = (const float*)d_in[7];
    const float* beta   = (const float*)d_in[8];
    const float* W_up   = (const float*)d_in[9];
    const float* W_upd1 = (const float*)d_in[10];
    const float* W_upd2 = (const float*)d_in[11];
    float* out = (float*)d_out;

    float* xres = (float*)d_ws;                       // NN*DD floats (8 MB)
    float* sf_r = xres + (size_t)NN * DD;             // NB*KK*DD floats (1 MB)
    float* sf_i = sf_r + (size_t)NB * KK * DD;        // NB*KK*DD floats (1 MB)

    hipMemsetAsync(sf_r, 0, (size_t)2 * NB * KK * DD * sizeof(float), stream);
    hipLaunchKernelGGL(k_premlp, dim3(NN / 32), dim3(256), 0, stream,
                       x, W_pre1, W_pre2, gamma, beta, xres);
    hipLaunchKernelGGL(k_scatter, dim3(NN / 64), dim3(256), 0, stream,
                       xres, kdr, damp, batch, sf_r, sf_i);
    hipLaunchKernelGGL(k_filter, dim3(NB * KK * DD / 256), dim3(256), 0, stream,
                       dp, W_up, sf_r, sf_i);
    hipLaunchKernelGGL(k_gather, dim3(NN / 32), dim3(256), 0, stream,
                       x, kdr, damp, batch, sf_r, sf_i, W_upd1, W_upd2, out);
}

// Round 2
// 177.756 us; speedup vs baseline: 1.2406x; 1.2406x over previous
//
#include <hip/hip_runtime.h>
#include <stdint.h>

#define NN 16384
#define KK 64
#define DD 128
#define PP 8
#define NB 32
#define CH 64
#define MAXCHUNK (NN / CH + NB)   // 288 worst case

typedef unsigned short ushort_t;
typedef __attribute__((ext_vector_type(8))) short short8;
typedef __attribute__((ext_vector_type(4))) float f32x4;

__device__ __forceinline__ ushort_t f2bf(float x) {
    unsigned u = __float_as_uint(x);
    u += 0x7fffu + ((u >> 16) & 1u);     // round-to-nearest-even
    return (ushort_t)(u >> 16);
}
__device__ __forceinline__ float silu_f(float v) { return v / (1.0f + __expf(-v)); }

// ---------------- prep: weight bf16 conversion + segment chunk worklist -----
__global__ void k_prep(const int* __restrict__ batch,
                       const float* __restrict__ W1, const float* __restrict__ W2,
                       const float* __restrict__ W3, const float* __restrict__ W4,
                       ushort_t* __restrict__ Wb, int4* __restrict__ wl,
                       int* __restrict__ nwl) {
    if (blockIdx.x == 0) {
        if (threadIdx.x == 0) {
            int idx = 0, start = 0;
            for (int b = 0; b < NB; ++b) {
                int lo = start, hi = NN;
                while (lo < hi) { int mid = (lo + hi) >> 1; if (batch[mid] <= b) lo = mid + 1; else hi = mid; }
                int end = lo;
                for (int r = start; r < end; r += CH) {
                    int4 e; e.x = b; e.y = r; e.z = min(CH, end - r); e.w = 0;
                    wl[idx++] = e;
                }
                start = end;
            }
            *nwl = idx;
        }
    } else {
        int w = blockIdx.x - 1;                 // 0..15
        const float* s = (w >> 2) == 0 ? W1 : (w >> 2) == 1 ? W2 : (w >> 2) == 2 ? W3 : W4;
        int off = (w & 3) * 4096;
        ushort_t* d = Wb + (size_t)(w >> 2) * 16384 + off;
        const float* sp = s + off;
        for (int i = threadIdx.x; i < 4096; i += 256) d[i] = f2bf(sp[i]);
    }
}

// ---------------- k1: pre-MLP (MFMA) + residual + LayerNorm -> xres bf16 ----
__global__ __launch_bounds__(256, 2) void k1_premlp(
        const float* __restrict__ x, const ushort_t* __restrict__ Wb,
        const float* __restrict__ gamma, const float* __restrict__ beta,
        ushort_t* __restrict__ xres_bf) {
    __shared__ __align__(16) ushort_t xsb[64][152];
    __shared__ __align__(16) ushort_t t1b[64][152];
    __shared__ float xf[64][DD];
    const int t = threadIdx.x, lane = t & 63, wv = t >> 6;
    const int n0 = blockIdx.x * 64;
    const ushort_t* W1b = Wb;
    const ushort_t* W2b = Wb + 16384;

    for (int i = t; i < 2048; i += 256) {
        float4 v = ((const float4*)(x + (size_t)n0 * DD))[i];
        int r = i >> 5, c = (i & 31) << 2;
        *(float4*)&xf[r][c] = v;
        xsb[r][c] = f2bf(v.x); xsb[r][c + 1] = f2bf(v.y);
        xsb[r][c + 2] = f2bf(v.z); xsb[r][c + 3] = f2bf(v.w);
    }
    __syncthreads();

    const int ar0 = wv * 16;
    const int fr = (lane >> 4) * 8, cr = lane & 15, rr4 = (lane >> 4) * 4;
    f32x4 acc[8];
    const f32x4 z4 = {0.f, 0.f, 0.f, 0.f};

    // GEMM1: silu(x @ W1^T)
#pragma unroll
    for (int nt = 0; nt < 8; ++nt) acc[nt] = z4;
#pragma unroll
    for (int ks = 0; ks < 4; ++ks) {
        short8 af = *(const short8*)&xsb[ar0 + cr][ks * 32 + fr];
#pragma unroll
        for (int nt = 0; nt < 8; ++nt) {
            short8 bf = *(const short8*)&W1b[(size_t)(nt * 16 + cr) * DD + ks * 32 + fr];
            acc[nt] = __builtin_amdgcn_mfma_f32_16x16x32_bf16(af, bf, acc[nt], 0, 0, 0);
        }
    }
#pragma unroll
    for (int nt = 0; nt < 8; ++nt)
#pragma unroll
        for (int r = 0; r < 4; ++r)
            t1b[ar0 + rr4 + r][nt * 16 + cr] = f2bf(silu_f(acc[nt][r]));
    __syncthreads();

    // GEMM2: silu(t1 @ W2^T), residual
#pragma unroll
    for (int nt = 0; nt < 8; ++nt) acc[nt] = z4;
#pragma unroll
    for (int ks = 0; ks < 4; ++ks) {
        short8 af = *(const short8*)&t1b[ar0 + cr][ks * 32 + fr];
#pragma unroll
        for (int nt = 0; nt < 8; ++nt) {
            short8 bf = *(const short8*)&W2b[(size_t)(nt * 16 + cr) * DD + ks * 32 + fr];
            acc[nt] = __builtin_amdgcn_mfma_f32_16x16x32_bf16(af, bf, acc[nt], 0, 0, 0);
        }
    }
#pragma unroll
    for (int nt = 0; nt < 8; ++nt)
#pragma unroll
        for (int r = 0; r < 4; ++r)
            xf[ar0 + rr4 + r][nt * 16 + cr] += silu_f(acc[nt][r]);
    __syncthreads();

    // LayerNorm rows -> bf16
    float g0 = gamma[lane], g1 = gamma[lane + 64];
    float be0 = beta[lane], be1 = beta[lane + 64];
    for (int r = wv; r < 64; r += 4) {
        float a = xf[r][lane], b = xf[r][lane + 64];
        float s = a + b, sq = a * a + b * b;
#pragma unroll
        for (int off = 32; off > 0; off >>= 1) { s += __shfl_xor(s, off); sq += __shfl_xor(sq, off); }
        float mu = s * (1.0f / 128.0f);
        float var = sq * (1.0f / 128.0f) - mu * mu;
        float rs = rsqrtf(var + 1e-5f);
        ushort_t* orow = xres_bf + (size_t)(n0 + r) * DD;
        orow[lane] = f2bf((a - mu) * rs * g0 + be0);
        orow[lane + 64] = f2bf((b - mu) * rs * g1 + be1);
    }
}

// ---------------- kT: trig + transposes ------------------------------------
__global__ __launch_bounds__(256, 4) void k_trigT(
        const float* __restrict__ kdr, const float* __restrict__ damp,
        const ushort_t* __restrict__ xres_bf,
        ushort_t* __restrict__ trig_rm, ushort_t* __restrict__ trigT,
        ushort_t* __restrict__ xresT) {
    __shared__ __align__(16) ushort_t tile[64][152];
    const int t = threadIdx.x;
    const int n0 = blockIdx.x * 64;

    // phase 1: trig -> tile + trig_rm
    for (int i = t; i < 2048; i += 256) {
        int r = i >> 5, kk = (i & 31) * 2;
        float2 kv = *(const float2*)&kdr[(size_t)(n0 + r) * KK + kk];
        float2 dv = *(const float2*)&damp[(size_t)(n0 + r) * KK + kk];
        float s0, c0, s1, c1;
        __sincosf(kv.x, &s0, &c0);
        __sincosf(kv.y, &s1, &c1);
        ushort_t rc0 = f2bf(c0 * dv.x), rc1 = f2bf(c1 * dv.y);
        ushort_t is0 = f2bf(s0 * dv.x), is1 = f2bf(s1 * dv.y);
        tile[r][kk] = rc0; tile[r][kk + 1] = rc1;
        tile[r][64 + kk] = is0; tile[r][64 + kk + 1] = is1;
        ushort2 a; a.x = rc0; a.y = rc1;
        ushort2 b; b.x = is0; b.y = is1;
        *(ushort2*)&trig_rm[(size_t)(n0 + r) * 128 + kk] = a;
        *(ushort2*)&trig_rm[(size_t)(n0 + r) * 128 + 64 + kk] = b;
    }
    __syncthreads();
    // phase 2: trigT[m][n0..n0+64)
    {
        int m = t >> 1, h = (t & 1) * 32;
#pragma unroll
        for (int q = 0; q < 4; ++q) {
            short8 v;
#pragma unroll
            for (int j = 0; j < 8; ++j) v[j] = (short)tile[h + q * 8 + j][m];
            *(short8*)&trigT[(size_t)m * NN + n0 + h + q * 8] = v;
        }
    }
    __syncthreads();
    // phase 3: xres tile
    for (int i = t; i < 1024; i += 256) {
        int r = i >> 4, c = (i & 15) * 8;
        *(short8*)&tile[r][c] = *(const short8*)&xres_bf[(size_t)(n0 + r) * DD + c];
    }
    __syncthreads();
    // phase 4: xresT[d][n0..n0+64)
    {
        int m = t >> 1, h = (t & 1) * 32;
#pragma unroll
        for (int q = 0; q < 4; ++q) {
            short8 v;
#pragma unroll
            for (int j = 0; j < 8; ++j) v[j] = (short)tile[h + q * 8 + j][m];
            *(short8*)&xresT[(size_t)m * NN + n0 + h + q * 8] = v;
        }
    }
}

// ---------------- k2: scatter  sfT[b][d][m] += sum_r xresT[d][r]*trigT[m][r]
__global__ __launch_bounds__(256, 3) void k2_scatter(
        const ushort_t* __restrict__ xresT, const ushort_t* __restrict__ trigT,
        const int4* __restrict__ wl, const int* __restrict__ nwl,
        float* __restrict__ sfT) {
    __shared__ __align__(16) ushort_t xt[128][88];
    __shared__ __align__(16) ushort_t tt[128][88];
    if (blockIdx.x >= *nwl) return;
    int4 e = wl[blockIdx.x];
    const int b = e.x, r0 = e.y, len = e.z;
    const int t = threadIdx.x, lane = t & 63, wv = t >> 6;

    for (int i = t; i < 512; i += 256) {
        int which = i >> 8, row = (i & 255) >> 1, h = (i & 1) * 32;
        const ushort_t* src = (which ? trigT : xresT) + (size_t)row * NN + r0 + h;
        ushort_t* dst = (which ? &tt[0][0] : &xt[0][0]) + row * 88 + h;
        if (len == CH) {
#pragma unroll
            for (int q = 0; q < 4; ++q) *(short8*)(dst + q * 8) = *(const short8*)(src + q * 8);
        } else {
            for (int j = 0; j < 32; ++j) { int c = h + j; dst[j] = (c < len) ? src[j] : (ushort_t)0; }
        }
    }
    __syncthreads();

    const int fr = (lane >> 4) * 8, cr = lane & 15, rr4 = (lane >> 4) * 4;
    const f32x4 z4 = {0.f, 0.f, 0.f, 0.f};
    f32x4 acc[2][8];
#pragma unroll
    for (int mt = 0; mt < 2; ++mt)
#pragma unroll
        for (int nt = 0; nt < 8; ++nt) acc[mt][nt] = z4;

#pragma unroll
    for (int ks = 0; ks < 2; ++ks) {
        short8 a0 = *(const short8*)&xt[wv * 32 + cr][ks * 32 + fr];
        short8 a1 = *(const short8*)&xt[wv * 32 + 16 + cr][ks * 32 + fr];
#pragma unroll
        for (int nt = 0; nt < 8; ++nt) {
            short8 bf = *(const short8*)&tt[nt * 16 + cr][ks * 32 + fr];
            acc[0][nt] = __builtin_amdgcn_mfma_f32_16x16x32_bf16(a0, bf, acc[0][nt], 0, 0, 0);
            acc[1][nt] = __builtin_amdgcn_mfma_f32_16x16x32_bf16(a1, bf, acc[1][nt], 0, 0, 0);
        }
    }
    float* dst = sfT + (size_t)b * 128 * 128;
#pragma unroll
    for (int mt = 0; mt < 2; ++mt)
#pragma unroll
        for (int nt = 0; nt < 8; ++nt)
#pragma unroll
            for (int r = 0; r < 4; ++r) {
                int d = wv * 32 + mt * 16 + rr4 + r, m = nt * 16 + cr;
                atomicAdd(&dst[d * 128 + m], acc[mt][nt][r]);
            }
}

// ---------------- k3: SFT = bf16(kfilter * sfT) -----------------------------
__global__ __launch_bounds__(256) void k3_filter(
        const float* __restrict__ dp, const float* __restrict__ wup,
        const float* __restrict__ sfT, ushort_t* __restrict__ SFTb) {
    int idx = blockIdx.x * 256 + threadIdx.x;   // b*16384 + d*128 + m
    int m = idx & 127, d = (idx >> 7) & 127;
    int k = m & 63;
    float kf = 0.0f;
#pragma unroll
    for (int p = 0; p < PP; ++p) kf = fmaf(dp[k * PP + p], wup[d * PP + p], kf);
    SFTb[idx] = f2bf(sfT[idx] * kf);
}

// ---------------- k4: gather  xg[n][d] = x + sum_m trig_rm[n][m]*SFT[b][d][m]
__global__ __launch_bounds__(256, 4) void k4_gather(
        const float* __restrict__ x, const ushort_t* __restrict__ trig_rm,
        const ushort_t* __restrict__ SFTb,
        const int4* __restrict__ wl, const int* __restrict__ nwl,
        float* __restrict__ xg) {
    __shared__ __align__(16) ushort_t sft[128][152];
    if (blockIdx.x >= *nwl) return;
    int4 e = wl[blockIdx.x];
    const int b = e.x, r0 = e.y, len = e.z;
    const int t = threadIdx.x, lane = t & 63, wv = t >> 6;

    const ushort_t* src = SFTb + (size_t)b * 16384;
    for (int i = t; i < 2048; i += 256) {
        int r = i >> 4, c = (i & 15) * 8;
        *(short8*)&sft[r][c] = *(const short8*)(src + r * 128 + c);
    }
    __syncthreads();

    const int fr = (lane >> 4) * 8, cr = lane & 15, rr4 = (lane >> 4) * 4;
    int nrow = r0 + wv * 16 + cr;
    if (nrow >= NN) nrow = NN - 1;
    const f32x4 z4 = {0.f, 0.f, 0.f, 0.f};
    f32x4 acc[8];
#pragma unroll
    for (int nt = 0; nt < 8; ++nt) acc[nt] = z4;
#pragma unroll
    for (int ks = 0; ks < 4; ++ks) {
        short8 af = *(const short8*)&trig_rm[(size_t)nrow * 128 + ks * 32 + fr];
#pragma unroll
        for (int nt = 0; nt < 8; ++nt) {
            short8 bf = *(const short8*)&sft[nt * 16 + cr][ks * 32 + fr];
            acc[nt] = __builtin_amdgcn_mfma_f32_16x16x32_bf16(af, bf, acc[nt], 0, 0, 0);
        }
    }
#pragma unroll
    for (int nt = 0; nt < 8; ++nt)
#pragma unroll
        for (int r = 0; r < 4; ++r) {
            int rr = wv * 16 + rr4 + r;
            if (rr < len) {
                size_t o = (size_t)(r0 + rr) * DD + nt * 16 + cr;
                xg[o] = x[o] + acc[nt][r];
            }
        }
}

// ---------------- k5: post-MLP + residual -> out ----------------------------
__global__ __launch_bounds__(256, 2) void k5_postmlp(
        const float* __restrict__ xg, const ushort_t* __restrict__ Wb,
        float* __restrict__ out) {
    __shared__ __align__(16) ushort_t xsb[64][152];
    __shared__ __align__(16) ushort_t t1b[64][152];
    __shared__ float xf[64][DD];
    const int t = threadIdx.x, lane = t & 63, wv = t >> 6;
    const int n0 = blockIdx.x * 64;
    const ushort_t* W3b = Wb + 32768;
    const ushort_t* W4b = Wb + 49152;

    for (int i = t; i < 2048; i += 256) {
        float4 v = ((const float4*)(xg + (size_t)n0 * DD))[i];
        int r = i >> 5, c = (i & 31) << 2;
        *(float4*)&xf[r][c] = v;
        xsb[r][c] = f2bf(v.x); xsb[r][c + 1] = f2bf(v.y);
        xsb[r][c + 2] = f2bf(v.z); xsb[r][c + 3] = f2bf(v.w);
    }
    __syncthreads();

    const int ar0 = wv * 16;
    const int fr = (lane >> 4) * 8, cr = lane & 15, rr4 = (lane >> 4) * 4;
    const f32x4 z4 = {0.f, 0.f, 0.f, 0.f};
    f32x4 acc[8];

#pragma unroll
    for (int nt = 0; nt < 8; ++nt) acc[nt] = z4;
#pragma unroll
    for (int ks = 0; ks < 4; ++ks) {
        short8 af = *(const short8*)&xsb[ar0 + cr][ks * 32 + fr];
#pragma unroll
        for (int nt = 0; nt < 8; ++nt) {
            short8 bf = *(const short8*)&W3b[(size_t)(nt * 16 + cr) * DD + ks * 32 + fr];
            acc[nt] = __builtin_amdgcn_mfma_f32_16x16x32_bf16(af, bf, acc[nt], 0, 0, 0);
        }
    }
#pragma unroll
    for (int nt = 0; nt < 8; ++nt)
#pragma unroll
        for (int r = 0; r < 4; ++r)
            t1b[ar0 + rr4 + r][nt * 16 + cr] = f2bf(silu_f(acc[nt][r]));
    __syncthreads();

#pragma unroll
    for (int nt = 0; nt < 8; ++nt) acc[nt] = z4;
#pragma unroll
    for (int ks = 0; ks < 4; ++ks) {
        short8 af = *(const short8*)&t1b[ar0 + cr][ks * 32 + fr];
#pragma unroll
        for (int nt = 0; nt < 8; ++nt) {
            short8 bf = *(const short8*)&W4b[(size_t)(nt * 16 + cr) * DD + ks * 32 + fr];
            acc[nt] = __builtin_amdgcn_mfma_f32_16x16x32_bf16(af, bf, acc[nt], 0, 0, 0);
        }
    }
#pragma unroll
    for (int nt = 0; nt < 8; ++nt)
#pragma unroll
        for (int r = 0; r < 4; ++r) {
            int rr = ar0 + rr4 + r, cc = nt * 16 + cr;
            out[(size_t)(n0 + rr) * DD + cc] = xf[rr][cc] + silu_f(acc[nt][r]);
        }
}

extern "C" void kernel_launch(void* const* d_in, const int* in_sizes, int n_in,
                              void* d_out, int out_size, void* d_ws, size_t ws_size,
                              hipStream_t stream) {
    const float* x      = (const float*)d_in[0];
    const float* kdr    = (const float*)d_in[1];
    const float* damp   = (const float*)d_in[2];
    const int*   batch  = (const int*)d_in[3];
    const float* dp     = (const float*)d_in[4];
    const float* W_pre1 = (const float*)d_in[5];
    const float* W_pre2 = (const float*)d_in[6];
    const float* gamma  = (const float*)d_in[7];
    const float* beta   = (const float*)d_in[8];
    const float* W_up   = (const float*)d_in[9];
    const float* W_upd1 = (const float*)d_in[10];
    const float* W_upd2 = (const float*)d_in[11];
    float* out = (float*)d_out;

    char* w = (char*)d_ws;
    ushort_t* Wb   = (ushort_t*)w;                         // 128 KiB
    int4*     wl   = (int4*)(w + 131072);                  // 8 KiB
    int*      nwl  = (int*)(w + 131072 + 8192);            // pad to 256B
    size_t o = 131072 + 8192 + 256;
    ushort_t* xres_bf = (ushort_t*)(w + o);  o += (size_t)NN * DD * 2;       // 4 MB
    ushort_t* trig_rm = (ushort_t*)(w + o);  o += (size_t)NN * 128 * 2;      // 4 MB
    ushort_t* trigT   = (ushort_t*)(w + o);  o += (size_t)128 * NN * 2;      // 4 MB
    ushort_t* xresT   = (ushort_t*)(w + o);  o += (size_t)128 * NN * 2;      // 4 MB
    float*    sfT     = (float*)(w + o);     o += (size_t)NB * 128 * 128 * 4; // 2 MB
    ushort_t* SFTb    = (ushort_t*)(w + o);  o += (size_t)NB * 128 * 128 * 2; // 1 MB
    float*    xg      = (float*)trigT;   // reuse trigT+xresT (8 MB), dead after k2

    hipMemsetAsync(sfT, 0, (size_t)NB * 128 * 128 * 4, stream);
    hipLaunchKernelGGL(k_prep, dim3(17), dim3(256), 0, stream,
                       batch, W_pre1, W_pre2, W_upd1, W_upd2, Wb, wl, nwl);
    hipLaunchKernelGGL(k1_premlp, dim3(NN / 64), dim3(256), 0, stream,
                       x, Wb, gamma, beta, xres_bf);
    hipLaunchKernelGGL(k_trigT, dim3(NN / 64), dim3(256), 0, stream,
                       kdr, damp, xres_bf, trig_rm, trigT, xresT);
    hipLaunchKernelGGL(k2_scatter, dim3(MAXCHUNK), dim3(256), 0, stream,
                       xresT, trigT, wl, nwl, sfT);
    hipLaunchKernelGGL(k3_filter, dim3(NB * 128 * 128 / 256), dim3(256), 0, stream,
                       dp, W_up, sfT, SFTb);
    hipLaunchKernelGGL(k4_gather, dim3(MAXCHUNK), dim3(256), 0, stream,
                       x, trig_rm, SFTb, wl, nwl, xg);
    hipLaunchKernelGGL(k5_postmlp, dim3(NN / 64), dim3(256), 0, stream,
                       xg, Wb, out);
}

// Round 3
// 108.100 us; speedup vs baseline: 2.0400x; 1.6444x over previous
//
#include <hip/hip_runtime.h>
#include <stdint.h>

#define NN 16384
#define KK 64
#define DD 128
#define PP 8
#define NB 32
#define CH 64
#define MAXCHUNK (NN / CH + NB)   // 288 worst case

typedef unsigned short ushort_t;
typedef __attribute__((ext_vector_type(8))) short short8;
typedef __attribute__((ext_vector_type(4))) float f32x4;

__device__ __forceinline__ ushort_t f2bf(float x) {
    unsigned u = __float_as_uint(x);
    u += 0x7fffu + ((u >> 16) & 1u);     // round-to-nearest-even
    return (ushort_t)(u >> 16);
}
__device__ __forceinline__ float silu_f(float v) { return v / (1.0f + __expf(-v)); }

// ---------------- prep: weight bf16 conversion + segment chunk worklist -----
// block 0: parallel worklist build (32 parallel binary searches + prefix sum)
// blocks 1..16: weight conversion
__global__ void k_prep(const int* __restrict__ batch,
                       const float* __restrict__ W1, const float* __restrict__ W2,
                       const float* __restrict__ W3, const float* __restrict__ W4,
                       ushort_t* __restrict__ Wb, int4* __restrict__ wl,
                       int* __restrict__ nwl) {
    if (blockIdx.x == 0) {
        __shared__ int starts[NB + 1];
        __shared__ int offs[NB + 1];
        const int t = threadIdx.x;
        if (t <= NB) {
            if (t == NB) {
                starts[NB] = NN;
            } else {
                int lo = 0, hi = NN;           // lower_bound: first i with batch[i] >= t
                while (lo < hi) {
                    int mid = (lo + hi) >> 1;
                    if (batch[mid] < t) lo = mid + 1; else hi = mid;
                }
                starts[t] = lo;
            }
        }
        __syncthreads();
        if (t == 0) {
            int off = 0;
            for (int b = 0; b < NB; ++b) {
                offs[b] = off;
                off += (starts[b + 1] - starts[b] + CH - 1) / CH;
            }
            offs[NB] = off;
            *nwl = off;
        }
        __syncthreads();
        if (t < NB) {
            int s = starts[t], e = starts[t + 1], o = offs[t];
            for (int r = s; r < e; r += CH) {
                int4 en; en.x = t; en.y = r; en.z = min(CH, e - r); en.w = 0;
                wl[o++] = en;
            }
        }
    } else {
        int w = blockIdx.x - 1;                 // 0..15
        const float* s = (w >> 2) == 0 ? W1 : (w >> 2) == 1 ? W2 : (w >> 2) == 2 ? W3 : W4;
        int off = (w & 3) * 4096;
        ushort_t* d = Wb + (size_t)(w >> 2) * 16384 + off;
        const float* sp = s + off;
        for (int i = threadIdx.x; i < 4096; i += 256) d[i] = f2bf(sp[i]);
    }
}

// ---------------- k1: pre-MLP (MFMA) + residual + LayerNorm -> xres bf16 ----
__global__ __launch_bounds__(256, 2) void k1_premlp(
        const float* __restrict__ x, const ushort_t* __restrict__ Wb,
        const float* __restrict__ gamma, const float* __restrict__ beta,
        ushort_t* __restrict__ xres_bf) {
    __shared__ __align__(16) ushort_t xsb[64][152];
    __shared__ __align__(16) ushort_t t1b[64][152];
    __shared__ float xf[64][DD];
    const int t = threadIdx.x, lane = t & 63, wv = t >> 6;
    const int n0 = blockIdx.x * 64;
    const ushort_t* W1b = Wb;
    const ushort_t* W2b = Wb + 16384;

    for (int i = t; i < 2048; i += 256) {
        float4 v = ((const float4*)(x + (size_t)n0 * DD))[i];
        int r = i >> 5, c = (i & 31) << 2;
        *(float4*)&xf[r][c] = v;
        xsb[r][c] = f2bf(v.x); xsb[r][c + 1] = f2bf(v.y);
        xsb[r][c + 2] = f2bf(v.z); xsb[r][c + 3] = f2bf(v.w);
    }
    __syncthreads();

    const int ar0 = wv * 16;
    const int fr = (lane >> 4) * 8, cr = lane & 15, rr4 = (lane >> 4) * 4;
    f32x4 acc[8];
    const f32x4 z4 = {0.f, 0.f, 0.f, 0.f};

    // GEMM1: silu(x @ W1^T)
#pragma unroll
    for (int nt = 0; nt < 8; ++nt) acc[nt] = z4;
#pragma unroll
    for (int ks = 0; ks < 4; ++ks) {
        short8 af = *(const short8*)&xsb[ar0 + cr][ks * 32 + fr];
#pragma unroll
        for (int nt = 0; nt < 8; ++nt) {
            short8 bf = *(const short8*)&W1b[(size_t)(nt * 16 + cr) * DD + ks * 32 + fr];
            acc[nt] = __builtin_amdgcn_mfma_f32_16x16x32_bf16(af, bf, acc[nt], 0, 0, 0);
        }
    }
#pragma unroll
    for (int nt = 0; nt < 8; ++nt)
#pragma unroll
        for (int r = 0; r < 4; ++r)
            t1b[ar0 + rr4 + r][nt * 16 + cr] = f2bf(silu_f(acc[nt][r]));
    __syncthreads();

    // GEMM2: silu(t1 @ W2^T), residual
#pragma unroll
    for (int nt = 0; nt < 8; ++nt) acc[nt] = z4;
#pragma unroll
    for (int ks = 0; ks < 4; ++ks) {
        short8 af = *(const short8*)&t1b[ar0 + cr][ks * 32 + fr];
#pragma unroll
        for (int nt = 0; nt < 8; ++nt) {
            short8 bf = *(const short8*)&W2b[(size_t)(nt * 16 + cr) * DD + ks * 32 + fr];
            acc[nt] = __builtin_amdgcn_mfma_f32_16x16x32_bf16(af, bf, acc[nt], 0, 0, 0);
        }
    }
#pragma unroll
    for (int nt = 0; nt < 8; ++nt)
#pragma unroll
        for (int r = 0; r < 4; ++r)
            xf[ar0 + rr4 + r][nt * 16 + cr] += silu_f(acc[nt][r]);
    __syncthreads();

    // LayerNorm rows -> bf16
    float g0 = gamma[lane], g1 = gamma[lane + 64];
    float be0 = beta[lane], be1 = beta[lane + 64];
    for (int r = wv; r < 64; r += 4) {
        float a = xf[r][lane], b = xf[r][lane + 64];
        float s = a + b, sq = a * a + b * b;
#pragma unroll
        for (int off = 32; off > 0; off >>= 1) { s += __shfl_xor(s, off); sq += __shfl_xor(sq, off); }
        float mu = s * (1.0f / 128.0f);
        float var = sq * (1.0f / 128.0f) - mu * mu;
        float rs = rsqrtf(var + 1e-5f);
        ushort_t* orow = xres_bf + (size_t)(n0 + r) * DD;
        orow[lane] = f2bf((a - mu) * rs * g0 + be0);
        orow[lane + 64] = f2bf((b - mu) * rs * g1 + be1);
    }
}

// ---------------- kT: trig + transposes ------------------------------------
__global__ __launch_bounds__(256, 4) void k_trigT(
        const float* __restrict__ kdr, const float* __restrict__ damp,
        const ushort_t* __restrict__ xres_bf,
        ushort_t* __restrict__ trig_rm, ushort_t* __restrict__ trigT,
        ushort_t* __restrict__ xresT) {
    __shared__ __align__(16) ushort_t tile[64][152];
    const int t = threadIdx.x;
    const int n0 = blockIdx.x * 64;

    // phase 1: trig -> tile + trig_rm
    for (int i = t; i < 2048; i += 256) {
        int r = i >> 5, kk = (i & 31) * 2;
        float2 kv = *(const float2*)&kdr[(size_t)(n0 + r) * KK + kk];
        float2 dv = *(const float2*)&damp[(size_t)(n0 + r) * KK + kk];
        float s0, c0, s1, c1;
        __sincosf(kv.x, &s0, &c0);
        __sincosf(kv.y, &s1, &c1);
        ushort_t rc0 = f2bf(c0 * dv.x), rc1 = f2bf(c1 * dv.y);
        ushort_t is0 = f2bf(s0 * dv.x), is1 = f2bf(s1 * dv.y);
        tile[r][kk] = rc0; tile[r][kk + 1] = rc1;
        tile[r][64 + kk] = is0; tile[r][64 + kk + 1] = is1;
        ushort2 a; a.x = rc0; a.y = rc1;
        ushort2 b; b.x = is0; b.y = is1;
        *(ushort2*)&trig_rm[(size_t)(n0 + r) * 128 + kk] = a;
        *(ushort2*)&trig_rm[(size_t)(n0 + r) * 128 + 64 + kk] = b;
    }
    __syncthreads();
    // phase 2: trigT[m][n0..n0+64)
    {
        int m = t >> 1, h = (t & 1) * 32;
#pragma unroll
        for (int q = 0; q < 4; ++q) {
            short8 v;
#pragma unroll
            for (int j = 0; j < 8; ++j) v[j] = (short)tile[h + q * 8 + j][m];
            *(short8*)&trigT[(size_t)m * NN + n0 + h + q * 8] = v;
        }
    }
    __syncthreads();
    // phase 3: xres tile
    for (int i = t; i < 1024; i += 256) {
        int r = i >> 4, c = (i & 15) * 8;
        *(short8*)&tile[r][c] = *(const short8*)&xres_bf[(size_t)(n0 + r) * DD + c];
    }
    __syncthreads();
    // phase 4: xresT[d][n0..n0+64)
    {
        int m = t >> 1, h = (t & 1) * 32;
#pragma unroll
        for (int q = 0; q < 4; ++q) {
            short8 v;
#pragma unroll
            for (int j = 0; j < 8; ++j) v[j] = (short)tile[h + q * 8 + j][m];
            *(short8*)&xresT[(size_t)m * NN + n0 + h + q * 8] = v;
        }
    }
}

// ---------------- k2: scatter  sfT[b][d][m] += sum_r xresT[d][r]*trigT[m][r]
__global__ __launch_bounds__(256, 3) void k2_scatter(
        const ushort_t* __restrict__ xresT, const ushort_t* __restrict__ trigT,
        const int4* __restrict__ wl, const int* __restrict__ nwl,
        float* __restrict__ sfT) {
    __shared__ __align__(16) ushort_t xt[128][88];
    __shared__ __align__(16) ushort_t tt[128][88];
    if (blockIdx.x >= *nwl) return;
    int4 e = wl[blockIdx.x];
    const int b = e.x, r0 = e.y, len = e.z;
    const int t = threadIdx.x, lane = t & 63, wv = t >> 6;

    for (int i = t; i < 512; i += 256) {
        int which = i >> 8, row = (i & 255) >> 1, h = (i & 1) * 32;
        const ushort_t* src = (which ? trigT : xresT) + (size_t)row * NN + r0 + h;
        ushort_t* dst = (which ? &tt[0][0] : &xt[0][0]) + row * 88 + h;
        if (len == CH) {
#pragma unroll
            for (int q = 0; q < 4; ++q) *(short8*)(dst + q * 8) = *(const short8*)(src + q * 8);
        } else {
            for (int j = 0; j < 32; ++j) { int c = h + j; dst[j] = (c < len) ? src[j] : (ushort_t)0; }
        }
    }
    __syncthreads();

    const int fr = (lane >> 4) * 8, cr = lane & 15, rr4 = (lane >> 4) * 4;
    const f32x4 z4 = {0.f, 0.f, 0.f, 0.f};
    f32x4 acc[2][8];
#pragma unroll
    for (int mt = 0; mt < 2; ++mt)
#pragma unroll
        for (int nt = 0; nt < 8; ++nt) acc[mt][nt] = z4;

#pragma unroll
    for (int ks = 0; ks < 2; ++ks) {
        short8 a0 = *(const short8*)&xt[wv * 32 + cr][ks * 32 + fr];
        short8 a1 = *(const short8*)&xt[wv * 32 + 16 + cr][ks * 32 + fr];
#pragma unroll
        for (int nt = 0; nt < 8; ++nt) {
            short8 bf = *(const short8*)&tt[nt * 16 + cr][ks * 32 + fr];
            acc[0][nt] = __builtin_amdgcn_mfma_f32_16x16x32_bf16(a0, bf, acc[0][nt], 0, 0, 0);
            acc[1][nt] = __builtin_amdgcn_mfma_f32_16x16x32_bf16(a1, bf, acc[1][nt], 0, 0, 0);
        }
    }
    float* dst = sfT + (size_t)b * 128 * 128;
#pragma unroll
    for (int mt = 0; mt < 2; ++mt)
#pragma unroll
        for (int nt = 0; nt < 8; ++nt)
#pragma unroll
            for (int r = 0; r < 4; ++r) {
                int d = wv * 32 + mt * 16 + rr4 + r, m = nt * 16 + cr;
                atomicAdd(&dst[d * 128 + m], acc[mt][nt][r]);
            }
}

// ---------------- k3: SFT = bf16(kfilter * sfT) -----------------------------
__global__ __launch_bounds__(256) void k3_filter(
        const float* __restrict__ dp, const float* __restrict__ wup,
        const float* __restrict__ sfT, ushort_t* __restrict__ SFTb) {
    int idx = blockIdx.x * 256 + threadIdx.x;   // b*16384 + d*128 + m
    int m = idx & 127, d = (idx >> 7) & 127;
    int k = m & 63;
    float kf = 0.0f;
#pragma unroll
    for (int p = 0; p < PP; ++p) kf = fmaf(dp[k * PP + p], wup[d * PP + p], kf);
    SFTb[idx] = f2bf(sfT[idx] * kf);
}

// ---------------- k4: gather  xg[n][d] = x + sum_m trig_rm[n][m]*SFT[b][d][m]
__global__ __launch_bounds__(256, 4) void k4_gather(
        const float* __restrict__ x, const ushort_t* __restrict__ trig_rm,
        const ushort_t* __restrict__ SFTb,
        const int4* __restrict__ wl, const int* __restrict__ nwl,
        float* __restrict__ xg) {
    __shared__ __align__(16) ushort_t sft[128][152];
    if (blockIdx.x >= *nwl) return;
    int4 e = wl[blockIdx.x];
    const int b = e.x, r0 = e.y, len = e.z;
    const int t = threadIdx.x, lane = t & 63, wv = t >> 6;

    const ushort_t* src = SFTb + (size_t)b * 16384;
    for (int i = t; i < 2048; i += 256) {
        int r = i >> 4, c = (i & 15) * 8;
        *(short8*)&sft[r][c] = *(const short8*)(src + r * 128 + c);
    }
    __syncthreads();

    const int fr = (lane >> 4) * 8, cr = lane & 15, rr4 = (lane >> 4) * 4;
    int nrow = r0 + wv * 16 + cr;
    if (nrow >= NN) nrow = NN - 1;
    const f32x4 z4 = {0.f, 0.f, 0.f, 0.f};
    f32x4 acc[8];
#pragma unroll
    for (int nt = 0; nt < 8; ++nt) acc[nt] = z4;
#pragma unroll
    for (int ks = 0; ks < 4; ++ks) {
        short8 af = *(const short8*)&trig_rm[(size_t)nrow * 128 + ks * 32 + fr];
#pragma unroll
        for (int nt = 0; nt < 8; ++nt) {
            short8 bf = *(const short8*)&sft[nt * 16 + cr][ks * 32 + fr];
            acc[nt] = __builtin_amdgcn_mfma_f32_16x16x32_bf16(af, bf, acc[nt], 0, 0, 0);
        }
    }
#pragma unroll
    for (int nt = 0; nt < 8; ++nt)
#pragma unroll
        for (int r = 0; r < 4; ++r) {
            int rr = wv * 16 + rr4 + r;
            if (rr < len) {
                size_t o = (size_t)(r0 + rr) * DD + nt * 16 + cr;
                xg[o] = x[o] + acc[nt][r];
            }
        }
}

// ---------------- k5: post-MLP + residual -> out ----------------------------
__global__ __launch_bounds__(256, 2) void k5_postmlp(
        const float* __restrict__ xg, const ushort_t* __restrict__ Wb,
        float* __restrict__ out) {
    __shared__ __align__(16) ushort_t xsb[64][152];
    __shared__ __align__(16) ushort_t t1b[64][152];
    __shared__ float xf[64][DD];
    const int t = threadIdx.x, lane = t & 63, wv = t >> 6;
    const int n0 = blockIdx.x * 64;
    const ushort_t* W3b = Wb + 32768;
    const ushort_t* W4b = Wb + 49152;

    for (int i = t; i < 2048; i += 256) {
        float4 v = ((const float4*)(xg + (size_t)n0 * DD))[i];
        int r = i >> 5, c = (i & 31) << 2;
        *(float4*)&xf[r][c] = v;
        xsb[r][c] = f2bf(v.x); xsb[r][c + 1] = f2bf(v.y);
        xsb[r][c + 2] = f2bf(v.z); xsb[r][c + 3] = f2bf(v.w);
    }
    __syncthreads();

    const int ar0 = wv * 16;
    const int fr = (lane >> 4) * 8, cr = lane & 15, rr4 = (lane >> 4) * 4;
    const f32x4 z4 = {0.f, 0.f, 0.f, 0.f};
    f32x4 acc[8];

#pragma unroll
    for (int nt = 0; nt < 8; ++nt) acc[nt] = z4;
#pragma unroll
    for (int ks = 0; ks < 4; ++ks) {
        short8 af = *(const short8*)&xsb[ar0 + cr][ks * 32 + fr];
#pragma unroll
        for (int nt = 0; nt < 8; ++nt) {
            short8 bf = *(const short8*)&W3b[(size_t)(nt * 16 + cr) * DD + ks * 32 + fr];
            acc[nt] = __builtin_amdgcn_mfma_f32_16x16x32_bf16(af, bf, acc[nt], 0, 0, 0);
        }
    }
#pragma unroll
    for (int nt = 0; nt < 8; ++nt)
#pragma unroll
        for (int r = 0; r < 4; ++r)
            t1b[ar0 + rr4 + r][nt * 16 + cr] = f2bf(silu_f(acc[nt][r]));
    __syncthreads();

#pragma unroll
    for (int nt = 0; nt < 8; ++nt) acc[nt] = z4;
#pragma unroll
    for (int ks = 0; ks < 4; ++ks) {
        short8 af = *(const short8*)&t1b[ar0 + cr][ks * 32 + fr];
#pragma unroll
        for (int nt = 0; nt < 8; ++nt) {
            short8 bf = *(const short8*)&W4b[(size_t)(nt * 16 + cr) * DD + ks * 32 + fr];
            acc[nt] = __builtin_amdgcn_mfma_f32_16x16x32_bf16(af, bf, acc[nt], 0, 0, 0);
        }
    }
#pragma unroll
    for (int nt = 0; nt < 8; ++nt)
#pragma unroll
        for (int r = 0; r < 4; ++r) {
            int rr = ar0 + rr4 + r, cc = nt * 16 + cr;
            out[(size_t)(n0 + rr) * DD + cc] = xf[rr][cc] + silu_f(acc[nt][r]);
        }
}

extern "C" void kernel_launch(void* const* d_in, const int* in_sizes, int n_in,
                              void* d_out, int out_size, void* d_ws, size_t ws_size,
                              hipStream_t stream) {
    const float* x      = (const float*)d_in[0];
    const float* kdr    = (const float*)d_in[1];
    const float* damp   = (const float*)d_in[2];
    const int*   batch  = (const int*)d_in[3];
    const float* dp     = (const float*)d_in[4];
    const float* W_pre1 = (const float*)d_in[5];
    const float* W_pre2 = (const float*)d_in[6];
    const float* gamma  = (const float*)d_in[7];
    const float* beta   = (const float*)d_in[8];
    const float* W_up   = (const float*)d_in[9];
    const float* W_upd1 = (const float*)d_in[10];
    const float* W_upd2 = (const float*)d_in[11];
    float* out = (float*)d_out;

    char* w = (char*)d_ws;
    ushort_t* Wb   = (ushort_t*)w;                         // 128 KiB
    int4*     wl   = (int4*)(w + 131072);                  // 8 KiB
    int*      nwl  = (int*)(w + 131072 + 8192);            // pad to 256B
    size_t o = 131072 + 8192 + 256;
    ushort_t* xres_bf = (ushort_t*)(w + o);  o += (size_t)NN * DD * 2;       // 4 MB
    ushort_t* trig_rm = (ushort_t*)(w + o);  o += (size_t)NN * 128 * 2;      // 4 MB
    ushort_t* trigT   = (ushort_t*)(w + o);  o += (size_t)128 * NN * 2;      // 4 MB
    ushort_t* xresT   = (ushort_t*)(w + o);  o += (size_t)128 * NN * 2;      // 4 MB
    float*    sfT     = (float*)(w + o);     o += (size_t)NB * 128 * 128 * 4; // 2 MB
    ushort_t* SFTb    = (ushort_t*)(w + o);  o += (size_t)NB * 128 * 128 * 2; // 1 MB
    float*    xg      = (float*)trigT;   // reuse trigT+xresT (8 MB), dead after k2

    hipMemsetAsync(sfT, 0, (size_t)NB * 128 * 128 * 4, stream);
    hipLaunchKernelGGL(k_prep, dim3(17), dim3(256), 0, stream,
                       batch, W_pre1, W_pre2, W_upd1, W_upd2, Wb, wl, nwl);
    hipLaunchKernelGGL(k1_premlp, dim3(NN / 64), dim3(256), 0, stream,
                       x, Wb, gamma, beta, xres_bf);
    hipLaunchKernelGGL(k_trigT, dim3(NN / 64), dim3(256), 0, stream,
                       kdr, damp, xres_bf, trig_rm, trigT, xresT);
    hipLaunchKernelGGL(k2_scatter, dim3(MAXCHUNK), dim3(256), 0, stream,
                       xresT, trigT, wl, nwl, sfT);
    hipLaunchKernelGGL(k3_filter, dim3(NB * 128 * 128 / 256), dim3(256), 0, stream,
                       dp, W_up, sfT, SFTb);
    hipLaunchKernelGGL(k4_gather, dim3(MAXCHUNK), dim3(256), 0, stream,
                       x, trig_rm, SFTb, wl, nwl, xg);
    hipLaunchKernelGGL(k5_postmlp, dim3(NN / 64), dim3(256), 0, stream,
                       xg, Wb, out);
}

// Round 4
// 105.139 us; speedup vs baseline: 2.0974x; 1.0282x over previous
//
#include <hip/hip_runtime.h>
#include <stdint.h>

#define NN 16384
#define KK 64
#define DD 128
#define PP 8
#define NB 32
#define CH 64
#define MAXCHUNK (NN / CH + NB)   // 288 worst case

typedef unsigned short ushort_t;
typedef __attribute__((ext_vector_type(8))) short short8;
typedef __attribute__((ext_vector_type(4))) float f32x4;

__device__ __forceinline__ ushort_t f2bf(float x) {
    unsigned u = __float_as_uint(x);
    u += 0x7fffu + ((u >> 16) & 1u);     // round-to-nearest-even
    return (ushort_t)(u >> 16);
}
__device__ __forceinline__ float silu_f(float v) { return v / (1.0f + __expf(-v)); }

// ---------------- prep: worklist + weight bf16 conversion + sfT zeroing -----
// block 0: parallel worklist build; blocks 1..16: weight conv; 17..144: zero sfT
__global__ void k_prep(const int* __restrict__ batch,
                       const float* __restrict__ W1, const float* __restrict__ W2,
                       const float* __restrict__ W3, const float* __restrict__ W4,
                       ushort_t* __restrict__ Wb, int4* __restrict__ wl,
                       int* __restrict__ nwl, float* __restrict__ sfT) {
    if (blockIdx.x == 0) {
        __shared__ int starts[NB + 1];
        __shared__ int offs[NB + 1];
        const int t = threadIdx.x;
        if (t <= NB) {
            if (t == NB) {
                starts[NB] = NN;
            } else {
                int lo = 0, hi = NN;           // lower_bound: first i with batch[i] >= t
                while (lo < hi) {
                    int mid = (lo + hi) >> 1;
                    if (batch[mid] < t) lo = mid + 1; else hi = mid;
                }
                starts[t] = lo;
            }
        }
        __syncthreads();
        if (t == 0) {
            int off = 0;
            for (int b = 0; b < NB; ++b) {
                offs[b] = off;
                off += (starts[b + 1] - starts[b] + CH - 1) / CH;
            }
            offs[NB] = off;
            *nwl = off;
        }
        __syncthreads();
        if (t < NB) {
            int s = starts[t], e = starts[t + 1], o = offs[t];
            for (int r = s; r < e; r += CH) {
                int4 en; en.x = t; en.y = r; en.z = min(CH, e - r); en.w = 0;
                wl[o++] = en;
            }
        }
    } else if (blockIdx.x <= 16) {
        int w = blockIdx.x - 1;                 // 0..15
        const float* s = (w >> 2) == 0 ? W1 : (w >> 2) == 1 ? W2 : (w >> 2) == 2 ? W3 : W4;
        int off = (w & 3) * 4096;
        ushort_t* d = Wb + (size_t)(w >> 2) * 16384 + off;
        const float* sp = s + off;
        for (int i = threadIdx.x; i < 4096; i += 256) d[i] = f2bf(sp[i]);
    } else {
        // zero sfT: 128 blocks x 256 threads x 4 float4 = 2 MB
        const f32x4 z4 = {0.f, 0.f, 0.f, 0.f};
        f32x4* dst = (f32x4*)sfT + (size_t)(blockIdx.x - 17) * 1024 + threadIdx.x;
#pragma unroll
        for (int q = 0; q < 4; ++q) dst[q * 256] = z4;
    }
}

// ---------------- k1: pre-MLP (MFMA) + residual + LayerNorm -> xres bf16 ----
__global__ __launch_bounds__(256, 2) void k1_premlp(
        const float* __restrict__ x, const ushort_t* __restrict__ Wb,
        const float* __restrict__ gamma, const float* __restrict__ beta,
        ushort_t* __restrict__ xres_bf) {
    __shared__ __align__(16) ushort_t xsb[64][152];
    __shared__ __align__(16) ushort_t t1b[64][152];
    __shared__ float xf[64][DD];
    const int t = threadIdx.x, lane = t & 63, wv = t >> 6;
    const int n0 = blockIdx.x * 64;
    const ushort_t* W1b = Wb;
    const ushort_t* W2b = Wb + 16384;

    for (int i = t; i < 2048; i += 256) {
        float4 v = ((const float4*)(x + (size_t)n0 * DD))[i];
        int r = i >> 5, c = (i & 31) << 2;
        *(float4*)&xf[r][c] = v;
        xsb[r][c] = f2bf(v.x); xsb[r][c + 1] = f2bf(v.y);
        xsb[r][c + 2] = f2bf(v.z); xsb[r][c + 3] = f2bf(v.w);
    }
    __syncthreads();

    const int ar0 = wv * 16;
    const int fr = (lane >> 4) * 8, cr = lane & 15, rr4 = (lane >> 4) * 4;
    f32x4 acc[8];
    const f32x4 z4 = {0.f, 0.f, 0.f, 0.f};

    // GEMM1: silu(x @ W1^T)
#pragma unroll
    for (int nt = 0; nt < 8; ++nt) acc[nt] = z4;
#pragma unroll
    for (int ks = 0; ks < 4; ++ks) {
        short8 af = *(const short8*)&xsb[ar0 + cr][ks * 32 + fr];
#pragma unroll
        for (int nt = 0; nt < 8; ++nt) {
            short8 bf = *(const short8*)&W1b[(size_t)(nt * 16 + cr) * DD + ks * 32 + fr];
            acc[nt] = __builtin_amdgcn_mfma_f32_16x16x32_bf16(af, bf, acc[nt], 0, 0, 0);
        }
    }
#pragma unroll
    for (int nt = 0; nt < 8; ++nt)
#pragma unroll
        for (int r = 0; r < 4; ++r)
            t1b[ar0 + rr4 + r][nt * 16 + cr] = f2bf(silu_f(acc[nt][r]));
    __syncthreads();

    // GEMM2: silu(t1 @ W2^T), residual
#pragma unroll
    for (int nt = 0; nt < 8; ++nt) acc[nt] = z4;
#pragma unroll
    for (int ks = 0; ks < 4; ++ks) {
        short8 af = *(const short8*)&t1b[ar0 + cr][ks * 32 + fr];
#pragma unroll
        for (int nt = 0; nt < 8; ++nt) {
            short8 bf = *(const short8*)&W2b[(size_t)(nt * 16 + cr) * DD + ks * 32 + fr];
            acc[nt] = __builtin_amdgcn_mfma_f32_16x16x32_bf16(af, bf, acc[nt], 0, 0, 0);
        }
    }
#pragma unroll
    for (int nt = 0; nt < 8; ++nt)
#pragma unroll
        for (int r = 0; r < 4; ++r)
            xf[ar0 + rr4 + r][nt * 16 + cr] += silu_f(acc[nt][r]);
    __syncthreads();

    // LayerNorm rows -> bf16
    float g0 = gamma[lane], g1 = gamma[lane + 64];
    float be0 = beta[lane], be1 = beta[lane + 64];
    for (int r = wv; r < 64; r += 4) {
        float a = xf[r][lane], b = xf[r][lane + 64];
        float s = a + b, sq = a * a + b * b;
#pragma unroll
        for (int off = 32; off > 0; off >>= 1) { s += __shfl_xor(s, off); sq += __shfl_xor(sq, off); }
        float mu = s * (1.0f / 128.0f);
        float var = sq * (1.0f / 128.0f) - mu * mu;
        float rs = rsqrtf(var + 1e-5f);
        ushort_t* orow = xres_bf + (size_t)(n0 + r) * DD;
        orow[lane] = f2bf((a - mu) * rs * g0 + be0);
        orow[lane + 64] = f2bf((b - mu) * rs * g1 + be1);
    }
}

// ---------------- kT: trig + transposes ------------------------------------
__global__ __launch_bounds__(256, 4) void k_trigT(
        const float* __restrict__ kdr, const float* __restrict__ damp,
        const ushort_t* __restrict__ xres_bf,
        ushort_t* __restrict__ trig_rm, ushort_t* __restrict__ trigT,
        ushort_t* __restrict__ xresT) {
    __shared__ __align__(16) ushort_t tile[64][152];
    const int t = threadIdx.x;
    const int n0 = blockIdx.x * 64;

    // phase 1: trig -> tile + trig_rm
    for (int i = t; i < 2048; i += 256) {
        int r = i >> 5, kk = (i & 31) * 2;
        float2 kv = *(const float2*)&kdr[(size_t)(n0 + r) * KK + kk];
        float2 dv = *(const float2*)&damp[(size_t)(n0 + r) * KK + kk];
        float s0, c0, s1, c1;
        __sincosf(kv.x, &s0, &c0);
        __sincosf(kv.y, &s1, &c1);
        ushort_t rc0 = f2bf(c0 * dv.x), rc1 = f2bf(c1 * dv.y);
        ushort_t is0 = f2bf(s0 * dv.x), is1 = f2bf(s1 * dv.y);
        tile[r][kk] = rc0; tile[r][kk + 1] = rc1;
        tile[r][64 + kk] = is0; tile[r][64 + kk + 1] = is1;
        ushort2 a; a.x = rc0; a.y = rc1;
        ushort2 b; b.x = is0; b.y = is1;
        *(ushort2*)&trig_rm[(size_t)(n0 + r) * 128 + kk] = a;
        *(ushort2*)&trig_rm[(size_t)(n0 + r) * 128 + 64 + kk] = b;
    }
    __syncthreads();
    // phase 2: trigT[m][n0..n0+64)
    {
        int m = t >> 1, h = (t & 1) * 32;
#pragma unroll
        for (int q = 0; q < 4; ++q) {
            short8 v;
#pragma unroll
            for (int j = 0; j < 8; ++j) v[j] = (short)tile[h + q * 8 + j][m];
            *(short8*)&trigT[(size_t)m * NN + n0 + h + q * 8] = v;
        }
    }
    __syncthreads();
    // phase 3: xres tile
    for (int i = t; i < 1024; i += 256) {
        int r = i >> 4, c = (i & 15) * 8;
        *(short8*)&tile[r][c] = *(const short8*)&xres_bf[(size_t)(n0 + r) * DD + c];
    }
    __syncthreads();
    // phase 4: xresT[d][n0..n0+64)
    {
        int m = t >> 1, h = (t & 1) * 32;
#pragma unroll
        for (int q = 0; q < 4; ++q) {
            short8 v;
#pragma unroll
            for (int j = 0; j < 8; ++j) v[j] = (short)tile[h + q * 8 + j][m];
            *(short8*)&xresT[(size_t)m * NN + n0 + h + q * 8] = v;
        }
    }
}

// ---------------- k2: scatter  sfT[b][d][m] += sum_r xresT[d][r]*trigT[m][r]
__global__ __launch_bounds__(256, 3) void k2_scatter(
        const ushort_t* __restrict__ xresT, const ushort_t* __restrict__ trigT,
        const int4* __restrict__ wl, const int* __restrict__ nwl,
        float* __restrict__ sfT) {
    __shared__ __align__(16) ushort_t xt[128][88];
    __shared__ __align__(16) ushort_t tt[128][88];
    if (blockIdx.x >= *nwl) return;
    int4 e = wl[blockIdx.x];
    const int b = e.x, r0 = e.y, len = e.z;
    const int t = threadIdx.x, lane = t & 63, wv = t >> 6;

    for (int i = t; i < 512; i += 256) {
        int which = i >> 8, row = (i & 255) >> 1, h = (i & 1) * 32;
        const ushort_t* src = (which ? trigT : xresT) + (size_t)row * NN + r0 + h;
        ushort_t* dst = (which ? &tt[0][0] : &xt[0][0]) + row * 88 + h;
        if (len == CH) {
#pragma unroll
            for (int q = 0; q < 4; ++q) *(short8*)(dst + q * 8) = *(const short8*)(src + q * 8);
        } else {
            for (int j = 0; j < 32; ++j) { int c = h + j; dst[j] = (c < len) ? src[j] : (ushort_t)0; }
        }
    }
    __syncthreads();

    const int fr = (lane >> 4) * 8, cr = lane & 15, rr4 = (lane >> 4) * 4;
    const f32x4 z4 = {0.f, 0.f, 0.f, 0.f};
    f32x4 acc[2][8];
#pragma unroll
    for (int mt = 0; mt < 2; ++mt)
#pragma unroll
        for (int nt = 0; nt < 8; ++nt) acc[mt][nt] = z4;

#pragma unroll
    for (int ks = 0; ks < 2; ++ks) {
        short8 a0 = *(const short8*)&xt[wv * 32 + cr][ks * 32 + fr];
        short8 a1 = *(const short8*)&xt[wv * 32 + 16 + cr][ks * 32 + fr];
#pragma unroll
        for (int nt = 0; nt < 8; ++nt) {
            short8 bf = *(const short8*)&tt[nt * 16 + cr][ks * 32 + fr];
            acc[0][nt] = __builtin_amdgcn_mfma_f32_16x16x32_bf16(a0, bf, acc[0][nt], 0, 0, 0);
            acc[1][nt] = __builtin_amdgcn_mfma_f32_16x16x32_bf16(a1, bf, acc[1][nt], 0, 0, 0);
        }
    }
    float* dst = sfT + (size_t)b * 128 * 128;
#pragma unroll
    for (int mt = 0; mt < 2; ++mt)
#pragma unroll
        for (int nt = 0; nt < 8; ++nt)
#pragma unroll
            for (int r = 0; r < 4; ++r) {
                int d = wv * 32 + mt * 16 + rr4 + r, m = nt * 16 + cr;
                atomicAdd(&dst[d * 128 + m], acc[mt][nt][r]);
            }
}

// ---------------- k3: SFT = bf16(kfilter * sfT) -----------------------------
__global__ __launch_bounds__(256) void k3_filter(
        const float* __restrict__ dp, const float* __restrict__ wup,
        const float* __restrict__ sfT, ushort_t* __restrict__ SFTb) {
    int idx = blockIdx.x * 256 + threadIdx.x;   // b*16384 + d*128 + m
    int m = idx & 127, d = (idx >> 7) & 127;
    int k = m & 63;
    float kf = 0.0f;
#pragma unroll
    for (int p = 0; p < PP; ++p) kf = fmaf(dp[k * PP + p], wup[d * PP + p], kf);
    SFTb[idx] = f2bf(sfT[idx] * kf);
}

// ---------------- k4: gather  xg[n][d] = x + sum_m trig_rm[n][m]*SFT[b][d][m]
__global__ __launch_bounds__(256, 4) void k4_gather(
        const float* __restrict__ x, const ushort_t* __restrict__ trig_rm,
        const ushort_t* __restrict__ SFTb,
        const int4* __restrict__ wl, const int* __restrict__ nwl,
        float* __restrict__ xg) {
    __shared__ __align__(16) ushort_t sft[128][152];
    if (blockIdx.x >= *nwl) return;
    int4 e = wl[blockIdx.x];
    const int b = e.x, r0 = e.y, len = e.z;
    const int t = threadIdx.x, lane = t & 63, wv = t >> 6;

    const ushort_t* src = SFTb + (size_t)b * 16384;
    for (int i = t; i < 2048; i += 256) {
        int r = i >> 4, c = (i & 15) * 8;
        *(short8*)&sft[r][c] = *(const short8*)(src + r * 128 + c);
    }
    __syncthreads();

    const int fr = (lane >> 4) * 8, cr = lane & 15, rr4 = (lane >> 4) * 4;
    int nrow = r0 + wv * 16 + cr;
    if (nrow >= NN) nrow = NN - 1;
    const f32x4 z4 = {0.f, 0.f, 0.f, 0.f};
    f32x4 acc[8];
#pragma unroll
    for (int nt = 0; nt < 8; ++nt) acc[nt] = z4;
#pragma unroll
    for (int ks = 0; ks < 4; ++ks) {
        short8 af = *(const short8*)&trig_rm[(size_t)nrow * 128 + ks * 32 + fr];
#pragma unroll
        for (int nt = 0; nt < 8; ++nt) {
            short8 bf = *(const short8*)&sft[nt * 16 + cr][ks * 32 + fr];
            acc[nt] = __builtin_amdgcn_mfma_f32_16x16x32_bf16(af, bf, acc[nt], 0, 0, 0);
        }
    }
#pragma unroll
    for (int nt = 0; nt < 8; ++nt)
#pragma unroll
        for (int r = 0; r < 4; ++r) {
            int rr = wv * 16 + rr4 + r;
            if (rr < len) {
                size_t o = (size_t)(r0 + rr) * DD + nt * 16 + cr;
                xg[o] = x[o] + acc[nt][r];
            }
        }
}

// ---------------- k5: post-MLP + residual -> out ----------------------------
__global__ __launch_bounds__(256, 2) void k5_postmlp(
        const float* __restrict__ xg, const ushort_t* __restrict__ Wb,
        float* __restrict__ out) {
    __shared__ __align__(16) ushort_t xsb[64][152];
    __shared__ __align__(16) ushort_t t1b[64][152];
    __shared__ float xf[64][DD];
    const int t = threadIdx.x, lane = t & 63, wv = t >> 6;
    const int n0 = blockIdx.x * 64;
    const ushort_t* W3b = Wb + 32768;
    const ushort_t* W4b = Wb + 49152;

    for (int i = t; i < 2048; i += 256) {
        float4 v = ((const float4*)(xg + (size_t)n0 * DD))[i];
        int r = i >> 5, c = (i & 31) << 2;
        *(float4*)&xf[r][c] = v;
        xsb[r][c] = f2bf(v.x); xsb[r][c + 1] = f2bf(v.y);
        xsb[r][c + 2] = f2bf(v.z); xsb[r][c + 3] = f2bf(v.w);
    }
    __syncthreads();

    const int ar0 = wv * 16;
    const int fr = (lane >> 4) * 8, cr = lane & 15, rr4 = (lane >> 4) * 4;
    const f32x4 z4 = {0.f, 0.f, 0.f, 0.f};
    f32x4 acc[8];

#pragma unroll
    for (int nt = 0; nt < 8; ++nt) acc[nt] = z4;
#pragma unroll
    for (int ks = 0; ks < 4; ++ks) {
        short8 af = *(const short8*)&xsb[ar0 + cr][ks * 32 + fr];
#pragma unroll
        for (int nt = 0; nt < 8; ++nt) {
            short8 bf = *(const short8*)&W3b[(size_t)(nt * 16 + cr) * DD + ks * 32 + fr];
            acc[nt] = __builtin_amdgcn_mfma_f32_16x16x32_bf16(af, bf, acc[nt], 0, 0, 0);
        }
    }
#pragma unroll
    for (int nt = 0; nt < 8; ++nt)
#pragma unroll
        for (int r = 0; r < 4; ++r)
            t1b[ar0 + rr4 + r][nt * 16 + cr] = f2bf(silu_f(acc[nt][r]));
    __syncthreads();

#pragma unroll
    for (int nt = 0; nt < 8; ++nt) acc[nt] = z4;
#pragma unroll
    for (int ks = 0; ks < 4; ++ks) {
        short8 af = *(const short8*)&t1b[ar0 + cr][ks * 32 + fr];
#pragma unroll
        for (int nt = 0; nt < 8; ++nt) {
            short8 bf = *(const short8*)&W4b[(size_t)(nt * 16 + cr) * DD + ks * 32 + fr];
            acc[nt] = __builtin_amdgcn_mfma_f32_16x16x32_bf16(af, bf, acc[nt], 0, 0, 0);
        }
    }
#pragma unroll
    for (int nt = 0; nt < 8; ++nt)
#pragma unroll
        for (int r = 0; r < 4; ++r) {
            int rr = ar0 + rr4 + r, cc = nt * 16 + cr;
            out[(size_t)(n0 + rr) * DD + cc] = xf[rr][cc] + silu_f(acc[nt][r]);
        }
}

extern "C" void kernel_launch(void* const* d_in, const int* in_sizes, int n_in,
                              void* d_out, int out_size, void* d_ws, size_t ws_size,
                              hipStream_t stream) {
    const float* x      = (const float*)d_in[0];
    const float* kdr    = (const float*)d_in[1];
    const float* damp   = (const float*)d_in[2];
    const int*   batch  = (const int*)d_in[3];
    const float* dp     = (const float*)d_in[4];
    const float* W_pre1 = (const float*)d_in[5];
    const float* W_pre2 = (const float*)d_in[6];
    const float* gamma  = (const float*)d_in[7];
    const float* beta   = (const float*)d_in[8];
    const float* W_up   = (const float*)d_in[9];
    const float* W_upd1 = (const float*)d_in[10];
    const float* W_upd2 = (const float*)d_in[11];
    float* out = (float*)d_out;

    char* w = (char*)d_ws;
    ushort_t* Wb   = (ushort_t*)w;                         // 128 KiB
    int4*     wl   = (int4*)(w + 131072);                  // 8 KiB
    int*      nwl  = (int*)(w + 131072 + 8192);            // pad to 256B
    size_t o = 131072 + 8192 + 256;
    ushort_t* xres_bf = (ushort_t*)(w + o);  o += (size_t)NN * DD * 2;       // 4 MB
    ushort_t* trig_rm = (ushort_t*)(w + o);  o += (size_t)NN * 128 * 2;      // 4 MB
    ushort_t* trigT   = (ushort_t*)(w + o);  o += (size_t)128 * NN * 2;      // 4 MB
    ushort_t* xresT   = (ushort_t*)(w + o);  o += (size_t)128 * NN * 2;      // 4 MB
    float*    sfT     = (float*)(w + o);     o += (size_t)NB * 128 * 128 * 4; // 2 MB
    ushort_t* SFTb    = (ushort_t*)(w + o);  o += (size_t)NB * 128 * 128 * 2; // 1 MB
    float*    xg      = (float*)trigT;   // reuse trigT+xresT (8 MB), dead after k2

    hipLaunchKernelGGL(k_prep, dim3(145), dim3(256), 0, stream,
                       batch, W_pre1, W_pre2, W_upd1, W_upd2, Wb, wl, nwl, sfT);
    hipLaunchKernelGGL(k1_premlp, dim3(NN / 64), dim3(256), 0, stream,
                       x, Wb, gamma, beta, xres_bf);
    hipLaunchKernelGGL(k_trigT, dim3(NN / 64), dim3(256), 0, stream,
                       kdr, damp, xres_bf, trig_rm, trigT, xresT);
    hipLaunchKernelGGL(k2_scatter, dim3(MAXCHUNK), dim3(256), 0, stream,
                       xresT, trigT, wl, nwl, sfT);
    hipLaunchKernelGGL(k3_filter, dim3(NB * 128 * 128 / 256), dim3(256), 0, stream,
                       dp, W_up, sfT, SFTb);
    hipLaunchKernelGGL(k4_gather, dim3(MAXCHUNK), dim3(256), 0, stream,
                       x, trig_rm, SFTb, wl, nwl, xg);
    hipLaunchKernelGGL(k5_postmlp, dim3(NN / 64), dim3(256), 0, stream,
                       xg, Wb, out);
}